// Round 6
// baseline (954.442 us; speedup 1.0000x reference)
//
#include <hip/hip_runtime.h>
#include <hip/hip_bf16.h>
#include <stdint.h>

// Problem geometry (fixed by reference)
#define NQ 4096      // 64*8*8 query rows
#define NS 40960     // 32768 (s1) + 8192 (s_src)
#define CDIM 512
#define QT 256       // q rows per block: 4 waves x 64 q (2 groups of 32)
#define SC 32        // s rows per chunk
#define NSPLIT 16    // s-dimension splits
#define SPER (NS / NSPLIT)   // 2560
#define NCHUNK (SPER / SC)   // 80
#define NCAND 480    // per-row candidates: 16 splits * 2 lane-halves * 15

typedef float f32x16 __attribute__((ext_vector_type(16)));
typedef __bf16 bf16x8 __attribute__((ext_vector_type(8)));
typedef unsigned int u32x4 __attribute__((ext_vector_type(4)));

__device__ __forceinline__ unsigned short f2bf(float f) {
    uint32_t u = __builtin_bit_cast(uint32_t, f);
    u += 0x7fffu + ((u >> 16) & 1u);   // RNE (finite values only here)
    return (unsigned short)(u >> 16);
}
__device__ __forceinline__ float bf2f(unsigned short u) {
    uint32_t x = ((uint32_t)u) << 16;
    return __builtin_bit_cast(float, x);
}

// CK-proven cast pattern: generic -> AS1/AS3 via uintptr
__device__ __forceinline__ void async_load16(const void* g, void* l) {
    auto gp = reinterpret_cast<const __attribute__((address_space(1))) uint32_t*>(
        reinterpret_cast<uintptr_t>(g));
    auto lp = reinterpret_cast<__attribute__((address_space(3))) uint32_t*>(
        reinterpret_cast<uintptr_t>(l));
    __builtin_amdgcn_global_load_lds(gp, lp, 16 /*bytes, literal*/, 0, 0);
}

// Branchless sorted-desc insert: r[i] = med3(v, r[i-1], r[i]) for i=14..1, then max.
// Inserting v <= r[14] is a provable no-op, so a wave-uniform __any guard is exact.
__device__ __forceinline__ void ins15(float (&r)[15], float v) {
#pragma unroll
    for (int i = 14; i >= 1; --i) r[i] = __builtin_amdgcn_fmed3f(v, r[i - 1], r[i]);
    r[0] = fmaxf(r[0], v);
}

// ---------------- Phase A1: pool q (4x4 mean) + row-normalize -> bf16 ----------------
// block = (image b, pool-row h): threads read 2 channels x 4 FULL 128B rows each ->
// every fetched line fully used (compulsory traffic only). grid 64*8=512.
__global__ __launch_bounds__(256) void pool_q_norm(const float* __restrict__ q,
                                                   unsigned short* __restrict__ qn) {
    int bb = blockIdx.x >> 3, h = blockIdx.x & 7;
    int t = threadIdx.x, lane = t & 63, wid = t >> 6;
    float vals[2][8];
    float ss[8] = {0, 0, 0, 0, 0, 0, 0, 0};
#pragma unroll
    for (int e = 0; e < 2; ++e) {
        int c = 2 * t + e;
        const float* base = q + ((size_t)(bb * 512 + c) * 1024 + 4 * h * 32);
#pragma unroll
        for (int w2 = 0; w2 < 8; ++w2) vals[e][w2] = 0.f;
#pragma unroll
        for (int i = 0; i < 4; ++i) {
            const float4* row = (const float4*)(base + i * 32);
#pragma unroll
            for (int w2 = 0; w2 < 8; ++w2) {
                float4 v = row[w2];
                vals[e][w2] += (v.x + v.y) + (v.z + v.w);
            }
        }
#pragma unroll
        for (int w2 = 0; w2 < 8; ++w2) {
            vals[e][w2] *= (1.f / 16.f);
            ss[w2] += vals[e][w2] * vals[e][w2];
        }
    }
    __shared__ float red[8][4];
#pragma unroll
    for (int k = 0; k < 8; ++k) {
        float v = ss[k];
#pragma unroll
        for (int o = 32; o > 0; o >>= 1) v += __shfl_xor(v, o, 64);
        if (lane == 0) red[k][wid] = v;
    }
    __syncthreads();
#pragma unroll
    for (int w2 = 0; w2 < 8; ++w2) {
        float inv = rsqrtf(red[w2][0] + red[w2][1] + red[w2][2] + red[w2][3]);
        ushort2 o2;
        o2.x = f2bf(vals[0][w2] * inv);
        o2.y = f2bf(vals[1][w2] * inv);
        *(ushort2*)(qn + (size_t)(bb * 64 + h * 8 + w2) * CDIM + 2 * t) = o2;
    }
}

// ------- Phase A2: pool S at BOTH scales + row-normalize -> bf16 -------
// block = (image b, src-row h2). 40 rows staged raw-bf16 in LDS [40][512];
// row sums via wave-per-row u32x4 reads + shuffle (all threads busy); then
// scaled coalesced stores. grid 128*8=1024.
__global__ __launch_bounds__(256) void pool_s_norm(const float* __restrict__ S,
                                                   unsigned short* __restrict__ sn) {
    int bb = blockIdx.x >> 3, h2 = blockIdx.x & 7;
    int t = threadIdx.x, lane = t & 63, wid = t >> 6;
    __shared__ unsigned short tile[40 * 512];   // 40KB raw-bf16 values
    __shared__ float rowsum[40];
#pragma unroll
    for (int e = 0; e < 2; ++e) {
        int c = 2 * t + e;
        const float* base = S + ((size_t)(bb * 512 + c) * 1024 + 4 * h2 * 32);
        float s1v[2][16];
#pragma unroll
        for (int j = 0; j < 2; ++j) {
            const float4* r0 = (const float4*)(base + (2 * j) * 32);
            const float4* r1 = (const float4*)(base + (2 * j + 1) * 32);
#pragma unroll
            for (int f = 0; f < 8; ++f) {
                float4 a = r0[f], b2 = r1[f];
                s1v[j][2 * f]     = (a.x + a.y + b2.x + b2.y) * 0.25f;
                s1v[j][2 * f + 1] = (a.z + a.w + b2.z + b2.w) * 0.25f;
            }
        }
#pragma unroll
        for (int j = 0; j < 2; ++j)
#pragma unroll
            for (int w1 = 0; w1 < 16; ++w1)
                tile[(j * 16 + w1) * 512 + c] = f2bf(s1v[j][w1]);
#pragma unroll
        for (int w2 = 0; w2 < 8; ++w2) {
            float src = (s1v[0][2 * w2] + s1v[0][2 * w2 + 1] +
                         s1v[1][2 * w2] + s1v[1][2 * w2 + 1]) * 0.25f;
            tile[(32 + w2) * 512 + c] = f2bf(src);
        }
    }
    __syncthreads();
    // Row sums-of-squares: wave wid owns rows 4k+wid; 64 lanes x 8 bf16 per row.
#pragma unroll
    for (int k = 0; k < 10; ++k) {
        int row = 4 * k + wid;
        u32x4 d = *(const u32x4*)(&tile[row * 512 + lane * 8]);
        float s = 0.f;
#pragma unroll
        for (int j = 0; j < 4; ++j) {
            float x0 = bf2f((unsigned short)(d[j] & 0xffffu));
            float x1 = bf2f((unsigned short)(d[j] >> 16));
            s += x0 * x0 + x1 * x1;
        }
#pragma unroll
        for (int o = 32; o > 0; o >>= 1) s += __shfl_xor(s, o, 64);
        if (lane == 0) rowsum[row] = s;
    }
    __syncthreads();
#pragma unroll
    for (int k = 0; k < 20; ++k) {
        int idx = t + 256 * k;
        int r = idx >> 7, seg = idx & 127;
        float inv = rsqrtf(rowsum[r]);
        const unsigned short* src = &tile[r * 512 + seg * 4];
        ushort4 o;
        o.x = f2bf(bf2f(src[0]) * inv);
        o.y = f2bf(bf2f(src[1]) * inv);
        o.z = f2bf(bf2f(src[2]) * inv);
        o.w = f2bf(bf2f(src[3]) * inv);
        int grow = (r < 32) ? (bb * 256 + (2 * h2 + (r >> 4)) * 16 + (r & 15))
                            : (32768 + bb * 64 + h2 * 8 + (r - 32));
        *(ushort4*)(sn + (size_t)grow * CDIM + seg * 4) = o;
    }
}

// ---------------- Phase B: swapped-operand 32x32x16 MFMA + in-register top-15 ----------------
// 256 blocks x 256 threads (4 waves x 64 q = 256-q tile), 1 block/CU.
// XCD-pinned: all 16 x-tiles of s-split y run on one XCD -> split streams once/XCD.
// Each LDS A-read feeds TWO MFMAs (q-groups b[0],b[1]) -> LDS read traffic halved.
// b[2][32] = 256 VGPR stays resident: 256 thr + launch_bounds(256,1) => 512-cap/wave.
// C layout (m74/m101): col=lane&31=q, row=(reg&3)+8*(reg>>2)+4*(lane>>5).
__global__ __launch_bounds__(256, 1) void sim_topk(const unsigned short* __restrict__ qn,
                                                   const unsigned short* __restrict__ sn,
                                                   float* __restrict__ partial) {
    __shared__ unsigned short Bs[2][SC * CDIM];   // 2 x 32KB, XOR-swizzled rows
    int id = blockIdx.x;
    int xcd = id & 7, j = id >> 3;
    int y = xcd * 2 + (j & 1);        // s-split, pinned to XCD
    int x = j >> 1;                   // q-tile 0..15
    int tid = threadIdx.x, lane = tid & 63, wid = tid >> 6;
    int rlo = lane & 31;
    int qbase = x * QT + wid * 64;
    int sbase = y * SPER;
    char* BsB = (char*)&Bs[0][0];
    const char* snB = (const char*)sn;

    // B fragments (q side): 2 groups x 32 q rows, full K=512. k = ks*16 + (lane>>5)*8 + e.
    u32x4 b[2][32];
#pragma unroll
    for (int g = 0; g < 2; ++g) {
        const unsigned short* qp = qn + (size_t)(qbase + g * 32 + rlo) * CDIM + ((lane >> 5) * 8);
#pragma unroll
        for (int ks = 0; ks < 32; ++ks) b[g][ks] = *(const u32x4*)(qp + ks * 16);
    }

    float r0[15], r1[15];
#pragma unroll
    for (int i = 0; i < 15; ++i) { r0[i] = -2.0f; r1[i] = -2.0f; }

    auto stage = [&](int ch, int buf) {
#pragma unroll
        for (int i = 0; i < 8; ++i) {
            int row = i * 4 + wid;                       // wave-uniform, 0..31
            size_t srcoff = ((size_t)(sbase + ch * SC + row) << 10)
                          + (size_t)((lane * 16) ^ ((row & 7) << 4));
            async_load16(snB + srcoff, BsB + buf * 32768 + row * 1024);
        }
    };

    int swz = (rlo & 7) << 4;
    int rowbase = rlo * 1024;
    int innerbase = (lane >> 5) * 16;

    stage(0, 0);
    stage(1, 1);
    for (int ch = 0; ch < NCHUNK; ++ch) {
        int buf = ch & 1;
        asm volatile("s_waitcnt vmcnt(8)" ::: "memory");   // chunk ch's loads landed
        __builtin_amdgcn_s_barrier();
        // Pin B-frags resident (defeat remat); zero-cost.
#pragma unroll
        for (int g = 0; g < 2; ++g)
#pragma unroll
            for (int ks = 0; ks < 32; ++ks) asm volatile("" : "+v"(b[g][ks]));
        const char* B0 = BsB + buf * 32768;
        f32x16 acc0, acc1;
#pragma unroll
        for (int e = 0; e < 16; ++e) { acc0[e] = 0.f; acc1[e] = 0.f; }
        __builtin_amdgcn_s_setprio(1);
#pragma unroll
        for (int ks = 0; ks < 32; ++ks) {
            int inner = (ks * 32 + innerbase) ^ swz;
            bf16x8 a = __builtin_bit_cast(bf16x8, *(const u32x4*)(B0 + rowbase + inner));
            acc0 = __builtin_amdgcn_mfma_f32_32x32x16_bf16(a, __builtin_bit_cast(bf16x8, b[0][ks]), acc0, 0, 0, 0);
            acc1 = __builtin_amdgcn_mfma_f32_32x32x16_bf16(a, __builtin_bit_cast(bf16x8, b[1][ks]), acc1, 0, 0, 0);
        }
        __builtin_amdgcn_s_setprio(0);
        __builtin_amdgcn_s_barrier();   // all reads of this buffer retired
        { int n = ch + 2; if (n >= NCHUNK) n -= NCHUNK; stage(n, buf); }  // refill freed buf
        // Scan overlaps the in-flight staging loads.
#pragma unroll
        for (int e = 0; e < 16; ++e) {
            float v0 = acc0[e];
            if (__any(v0 > r0[14])) ins15(r0, v0);
            float v1 = acc1[e];
            if (__any(v1 > r1[14])) ins15(r1, v1);
        }
    }

    // Emit: partial[qrow][split][sub][15], sub = lane>>5
    int q0 = qbase + rlo;
    float* dst0 = partial + (((size_t)q0 * NSPLIT + y) * 2 + (lane >> 5)) * 15;
    float* dst1 = partial + (((size_t)(q0 + 32) * NSPLIT + y) * 2 + (lane >> 5)) * 15;
#pragma unroll
    for (int i = 0; i < 15; ++i) { dst0[i] = r0[i]; dst1[i] = r1[i]; }
}

// ---------------- Final: merge 480 candidates/row -> top15 -> LSE/top4 loss ----------------
// Wave per row, 4 rows/block, no per-round barriers, one atomicAdd per block.
__global__ __launch_bounds__(256) void topk_loss(const float* __restrict__ partial,
                                                 float* __restrict__ accum) {
    int t = threadIdx.x, lane = t & 63, wid = t >> 6;
    int r = blockIdx.x * 4 + wid;
    const float* src = partial + (size_t)r * NCAND;
    float v[8];
#pragma unroll
    for (int i = 0; i < 8; ++i) {
        int idx = lane + 64 * i;
        v[i] = (idx < NCAND) ? src[idx] : -1e30f;
    }
    float m0 = 0.f, sexp = 0.f, top4 = 0.f;
#pragma unroll
    for (int round = 0; round < 15; ++round) {
        float m = v[0];
        int mi = lane * 8;
#pragma unroll
        for (int i = 1; i < 8; ++i)
            if (v[i] > m) { m = v[i]; mi = lane * 8 + i; }
#pragma unroll
        for (int o = 32; o > 0; o >>= 1) {
            float om = __shfl_xor(m, o, 64);
            int oi = __shfl_xor(mi, o, 64);
            if (om > m || (om == m && oi < mi)) { m = om; mi = oi; }
        }
        int wl = mi >> 3, wi = mi & 7;
#pragma unroll
        for (int i = 0; i < 8; ++i)
            if (i == wi && wl == lane) v[i] = -1e30f;   // static-index clear
        if (round == 0) m0 = m;
        sexp += expf(m - m0);
        if (round < 4) top4 += m;
    }
    float loss = m0 + logf(sexp) - 0.25f * top4;
    __shared__ float red[4];
    if (lane == 0) red[wid] = loss;
    __syncthreads();
    if (t == 0) atomicAdd(accum, red[0] + red[1] + red[2] + red[3]);
}

__global__ void finalize_out(const float* __restrict__ accum, float* __restrict__ out) {
    out[0] = accum[0] * (1.0f / (float)NQ);
}

// ---------------- Launch ----------------
extern "C" void kernel_launch(void* const* d_in, const int* in_sizes, int n_in,
                              void* d_out, int out_size, void* d_ws, size_t ws_size,
                              hipStream_t stream) {
    (void)in_sizes; (void)n_in; (void)out_size; (void)ws_size;
    const float* q = (const float*)d_in[0];
    const float* S = (const float*)d_in[1];
    char* ws = (char*)d_ws;
    unsigned short* qn = (unsigned short*)ws;                        // 4,194,304 B
    unsigned short* sn = (unsigned short*)(ws + 4194304);            // 41,943,040 B
    float* partial = (float*)(ws + 4194304 + 41943040);              // 7,864,320 B
    float* accum   = (float*)(ws + 4194304 + 41943040 + 7864320);    // 4 B

    hipMemsetAsync(accum, 0, 4, stream);
    pool_q_norm<<<512, 256, 0, stream>>>(q, qn);
    pool_s_norm<<<1024, 256, 0, stream>>>(S, sn);
    sim_topk<<<256, 256, 0, stream>>>(qn, sn, partial);
    topk_loss<<<NQ / 4, 256, 0, stream>>>(partial, accum);
    finalize_out<<<1, 1, 0, stream>>>(accum, (float*)d_out);
}

// Round 9
// 347.383 us; speedup vs baseline: 2.7475x; 2.7475x over previous
//
#include <hip/hip_runtime.h>
#include <hip/hip_bf16.h>
#include <stdint.h>

// Problem geometry (fixed by reference)
#define NQ 4096      // 64*8*8 query rows
#define NS 40960     // 32768 (s1) + 8192 (s_src)
#define CDIM 512
#define QT 512       // q rows per block: 8 waves x 64 q (2 groups of 32)
#define SC 64        // s rows per chunk
#define NSPLIT 32    // s-dimension splits
#define SPER (NS / NSPLIT)   // 1280
#define NCHUNK (SPER / SC)   // 20
#define NCAND 960    // per-row candidates: 32 splits * 2 lane-halves * 15

typedef float f32x16 __attribute__((ext_vector_type(16)));
typedef unsigned int u32x4 __attribute__((ext_vector_type(4)));
typedef unsigned int u32x2 __attribute__((ext_vector_type(2)));

__device__ __forceinline__ unsigned short f2bf(float f) {
    uint32_t u = __builtin_bit_cast(uint32_t, f);
    u += 0x7fffu + ((u >> 16) & 1u);   // RNE (finite values only here)
    return (unsigned short)(u >> 16);
}
__device__ __forceinline__ float bf2f(unsigned short u) {
    uint32_t x = ((uint32_t)u) << 16;
    return __builtin_bit_cast(float, x);
}
// k-permutation baked into BOTH qn and sn fp8 layouts (dot-product invariant):
// swap bits 3,4 of the channel index so one 16B LDS slot holds the two 8B
// MFMA operands (m=2kk, 2kk+1) for a lane's k-half.
__device__ __forceinline__ int kperm(int c) {
    return (c & ~24) | ((c & 8) << 1) | ((c & 16) >> 1);
}

// CK-proven cast pattern: generic -> AS1/AS3 via uintptr
__device__ __forceinline__ void async_load16(const void* g, void* l) {
    auto gp = reinterpret_cast<const __attribute__((address_space(1))) uint32_t*>(
        reinterpret_cast<uintptr_t>(g));
    auto lp = reinterpret_cast<__attribute__((address_space(3))) uint32_t*>(
        reinterpret_cast<uintptr_t>(l));
    __builtin_amdgcn_global_load_lds(gp, lp, 16 /*bytes, literal*/, 0, 0);
}

// Branchless sorted-desc insert: r[i] = med3(v, r[i-1], r[i]) for i=14..1, then max.
// Inserting v <= r[14] is a provable no-op, so a wave-uniform __any guard is exact.
__device__ __forceinline__ void ins15(float (&r)[15], float v) {
#pragma unroll
    for (int i = 14; i >= 1; --i) r[i] = __builtin_amdgcn_fmed3f(v, r[i - 1], r[i]);
    r[0] = fmaxf(r[0], v);
}

// ---------------- Phase A1: pool q (4x4 mean) + row-normalize -> fp8 (k-permuted) ----------------
__global__ __launch_bounds__(256) void pool_q_norm(const float* __restrict__ q,
                                                   char* __restrict__ qn) {
    int bb = blockIdx.x >> 3, h = blockIdx.x & 7;
    int t = threadIdx.x, lane = t & 63, wid = t >> 6;
    float vals[2][8];
    float ss[8] = {0, 0, 0, 0, 0, 0, 0, 0};
#pragma unroll
    for (int e = 0; e < 2; ++e) {
        int c = 2 * t + e;
        const float* base = q + ((size_t)(bb * 512 + c) * 1024 + 4 * h * 32);
#pragma unroll
        for (int w2 = 0; w2 < 8; ++w2) vals[e][w2] = 0.f;
#pragma unroll
        for (int i = 0; i < 4; ++i) {
            const float4* row = (const float4*)(base + i * 32);
#pragma unroll
            for (int w2 = 0; w2 < 8; ++w2) {
                float4 v = row[w2];
                vals[e][w2] += (v.x + v.y) + (v.z + v.w);
            }
        }
#pragma unroll
        for (int w2 = 0; w2 < 8; ++w2) {
            vals[e][w2] *= (1.f / 16.f);
            ss[w2] += vals[e][w2] * vals[e][w2];
        }
    }
    __shared__ float red[8][4];
#pragma unroll
    for (int k = 0; k < 8; ++k) {
        float v = ss[k];
#pragma unroll
        for (int o = 32; o > 0; o >>= 1) v += __shfl_xor(v, o, 64);
        if (lane == 0) red[k][wid] = v;
    }
    __syncthreads();
    int cp = kperm(2 * t);
#pragma unroll
    for (int w2 = 0; w2 < 8; ++w2) {
        float inv = rsqrtf(red[w2][0] + red[w2][1] + red[w2][2] + red[w2][3]);
        int p = __builtin_amdgcn_cvt_pk_fp8_f32(vals[0][w2] * inv, vals[1][w2] * inv, 0, false);
        *(unsigned short*)(qn + (size_t)(bb * 64 + h * 8 + w2) * 512 + cp) = (unsigned short)(p & 0xffff);
    }
}

// ------- Phase A2: pool S at BOTH scales + row-normalize -> fp8 (k-permuted) -------
__global__ __launch_bounds__(256) void pool_s_norm(const float* __restrict__ S,
                                                   char* __restrict__ sn) {
    int bb = blockIdx.x >> 3, h2 = blockIdx.x & 7;
    int t = threadIdx.x, lane = t & 63, wid = t >> 6;
    __shared__ unsigned short tile[40 * 512];   // 40KB raw-bf16 values
    __shared__ float rowsum[40];
#pragma unroll
    for (int e = 0; e < 2; ++e) {
        int c = 2 * t + e;
        const float* base = S + ((size_t)(bb * 512 + c) * 1024 + 4 * h2 * 32);
        float s1v[2][16];
#pragma unroll
        for (int j = 0; j < 2; ++j) {
            const float4* r0 = (const float4*)(base + (2 * j) * 32);
            const float4* r1 = (const float4*)(base + (2 * j + 1) * 32);
#pragma unroll
            for (int f = 0; f < 8; ++f) {
                float4 a = r0[f], b2 = r1[f];
                s1v[j][2 * f]     = (a.x + a.y + b2.x + b2.y) * 0.25f;
                s1v[j][2 * f + 1] = (a.z + a.w + b2.z + b2.w) * 0.25f;
            }
        }
#pragma unroll
        for (int j = 0; j < 2; ++j)
#pragma unroll
            for (int w1 = 0; w1 < 16; ++w1)
                tile[(j * 16 + w1) * 512 + c] = f2bf(s1v[j][w1]);
#pragma unroll
        for (int w2 = 0; w2 < 8; ++w2) {
            float src = (s1v[0][2 * w2] + s1v[0][2 * w2 + 1] +
                         s1v[1][2 * w2] + s1v[1][2 * w2 + 1]) * 0.25f;
            tile[(32 + w2) * 512 + c] = f2bf(src);
        }
    }
    __syncthreads();
    // Row sums-of-squares: wave wid owns rows 4k+wid; 64 lanes x 8 bf16 per row.
#pragma unroll
    for (int k = 0; k < 10; ++k) {
        int row = 4 * k + wid;
        u32x4 d = *(const u32x4*)(&tile[row * 512 + lane * 8]);
        float s = 0.f;
#pragma unroll
        for (int j = 0; j < 4; ++j) {
            float x0 = bf2f((unsigned short)(d[j] & 0xffffu));
            float x1 = bf2f((unsigned short)(d[j] >> 16));
            s += x0 * x0 + x1 * x1;
        }
#pragma unroll
        for (int o = 32; o > 0; o >>= 1) s += __shfl_xor(s, o, 64);
        if (lane == 0) rowsum[row] = s;
    }
    __syncthreads();
    // Scale + fp8 cast + k-permuted coalesced 8B stores: 40 rows x 64 segs.
#pragma unroll
    for (int k = 0; k < 10; ++k) {
        int idx = t + 256 * k;
        int r = idx >> 6, seg = idx & 63;
        float inv = rsqrtf(rowsum[r]);
        const unsigned short* src = &tile[r * 512 + seg * 8];
        float x[8];
#pragma unroll
        for (int m = 0; m < 8; ++m) x[m] = bf2f(src[m]) * inv;
        unsigned int w0 = (unsigned int)__builtin_amdgcn_cvt_pk_fp8_f32(
            x[2], x[3], __builtin_amdgcn_cvt_pk_fp8_f32(x[0], x[1], 0, false), true);
        unsigned int w1 = (unsigned int)__builtin_amdgcn_cvt_pk_fp8_f32(
            x[6], x[7], __builtin_amdgcn_cvt_pk_fp8_f32(x[4], x[5], 0, false), true);
        int nseg = (seg & ~3) | ((seg & 1) << 1) | ((seg >> 1) & 1);   // swap k-bits 3,4
        int grow = (r < 32) ? (bb * 256 + (2 * h2 + (r >> 4)) * 16 + (r & 15))
                            : (32768 + bb * 64 + h2 * 8 + (r - 32));
        uint2 o2; o2.x = w0; o2.y = w1;
        *(uint2*)(sn + (size_t)grow * 512 + nseg * 8) = o2;
    }
}

// ---------------- Phase B: fp8 32x32x16 MFMA + in-register top-15 ----------------
// 256 blocks x 512 threads (8 waves x 64 q = 512-q tile), 1 block/CU.
// XCD-pinned: the 8 x-tiles of s-split y run on one XCD (id&7); each 640KB fp8
// split streams from HBM once per XCD then L2-hits.
// LDS chunk = 64 s-rows x 512B fp8 = 32KB (dbuf). Each 16B A-read feeds 4 MFMAs
// (2 k-halves x 2 q-groups). b[2][16] u32x4 = 128 VGPR (fits the 256 arch cap —
// the R3/R6 bf16 2-group attempt needed 256 and spilled).
// Full slot^(row&31) swizzle: conflict-bounded ds_read_b128.
__global__ __launch_bounds__(512, 1) void sim_topk(const char* __restrict__ qn,
                                                   const char* __restrict__ sn,
                                                   float* __restrict__ partial) {
    __shared__ char Bs[2][SC * 512];   // 2 x 32KB
    int id = blockIdx.x;
    int xcd = id & 7, j = id >> 3;
    int y = xcd * 4 + (j & 3);        // s-split 0..31, pinned to XCD
    int x = j >> 2;                   // q-tile 0..7
    int tid = threadIdx.x, lane = tid & 63, wid = tid >> 6;
    int rlo = lane & 31, hi = lane >> 5;
    int qbase = x * QT + wid * 64;
    int sbase = y * SPER;
    char* BsB = &Bs[0][0];

    // B fragments (q side, fp8): 2 groups x 32 q rows, full K=512 (k-permuted layout).
    // One u32x4 per (g,kk) covers MFMAs 2kk (lo u64) and 2kk+1 (hi u64).
    u32x4 b[2][16];
#pragma unroll
    for (int g = 0; g < 2; ++g) {
        const char* qp = qn + (size_t)(qbase + g * 32 + rlo) * 512 + hi * 16;
#pragma unroll
        for (int kk = 0; kk < 16; ++kk) b[g][kk] = *(const u32x4*)(qp + kk * 32);
    }

    float r0[15], r1[15];
#pragma unroll
    for (int i = 0; i < 15; ++i) { r0[i] = -2.0f; r1[i] = -2.0f; }

    auto stage = [&](int ch, int buf) {
#pragma unroll
        for (int ii = 0; ii < 4; ++ii) {
            int i = wid * 4 + ii;                 // wave-uniform instr idx, 2 rows each
            int row = 2 * i + hi;
            size_t srcoff = (size_t)(sbase + ch * SC + row) * 512
                          + (size_t)((rlo ^ (row & 31)) * 16);
            async_load16(sn + srcoff, BsB + buf * 32768 + i * 1024);
        }
    };

    stage(0, 0);
    stage(1, 1);
    for (int ch = 0; ch < NCHUNK; ++ch) {
        int buf = ch & 1;
        asm volatile("s_waitcnt vmcnt(4)" ::: "memory");   // chunk ch's loads landed
        __builtin_amdgcn_s_barrier();
        // Pin B-frags resident (defeat remat); zero-cost.
#pragma unroll
        for (int g = 0; g < 2; ++g)
#pragma unroll
            for (int kk = 0; kk < 16; ++kk) asm volatile("" : "+v"(b[g][kk]));
        const char* B0 = BsB + buf * 32768;
        f32x16 a00, a01, a10, a11;   // acc[sgroup][qgroup]
#pragma unroll
        for (int e = 0; e < 16; ++e) { a00[e] = 0.f; a01[e] = 0.f; a10[e] = 0.f; a11[e] = 0.f; }
        __builtin_amdgcn_s_setprio(1);
#pragma unroll
        for (int kk = 0; kk < 16; ++kk) {
            int slot = ((kk * 2 + hi) ^ rlo) * 16;
            u32x4 aA = *(const u32x4*)(B0 + rlo * 512 + slot);
            u32x4 aB = *(const u32x4*)(B0 + (32 + rlo) * 512 + slot);
            long aAlo = __builtin_bit_cast(long, (u32x2){aA[0], aA[1]});
            long aAhi = __builtin_bit_cast(long, (u32x2){aA[2], aA[3]});
            long aBlo = __builtin_bit_cast(long, (u32x2){aB[0], aB[1]});
            long aBhi = __builtin_bit_cast(long, (u32x2){aB[2], aB[3]});
            long b0lo = __builtin_bit_cast(long, (u32x2){b[0][kk][0], b[0][kk][1]});
            long b0hi = __builtin_bit_cast(long, (u32x2){b[0][kk][2], b[0][kk][3]});
            long b1lo = __builtin_bit_cast(long, (u32x2){b[1][kk][0], b[1][kk][1]});
            long b1hi = __builtin_bit_cast(long, (u32x2){b[1][kk][2], b[1][kk][3]});
            a00 = __builtin_amdgcn_mfma_f32_32x32x16_fp8_fp8(aAlo, b0lo, a00, 0, 0, 0);
            a00 = __builtin_amdgcn_mfma_f32_32x32x16_fp8_fp8(aAhi, b0hi, a00, 0, 0, 0);
            a01 = __builtin_amdgcn_mfma_f32_32x32x16_fp8_fp8(aAlo, b1lo, a01, 0, 0, 0);
            a01 = __builtin_amdgcn_mfma_f32_32x32x16_fp8_fp8(aAhi, b1hi, a01, 0, 0, 0);
            a10 = __builtin_amdgcn_mfma_f32_32x32x16_fp8_fp8(aBlo, b0lo, a10, 0, 0, 0);
            a10 = __builtin_amdgcn_mfma_f32_32x32x16_fp8_fp8(aBhi, b0hi, a10, 0, 0, 0);
            a11 = __builtin_amdgcn_mfma_f32_32x32x16_fp8_fp8(aBlo, b1lo, a11, 0, 0, 0);
            a11 = __builtin_amdgcn_mfma_f32_32x32x16_fp8_fp8(aBhi, b1hi, a11, 0, 0, 0);
        }
        __builtin_amdgcn_s_setprio(0);
        __builtin_amdgcn_s_barrier();   // all reads of this buffer retired
        { int n = ch + 2; if (n >= NCHUNK) n -= NCHUNK; stage(n, buf); }  // refill freed buf
        // Scan overlaps the in-flight staging loads. List = q-group.
#pragma unroll
        for (int e = 0; e < 16; ++e) {
            float v;
            v = a00[e]; if (__any(v > r0[14])) ins15(r0, v);
            v = a10[e]; if (__any(v > r0[14])) ins15(r0, v);
            v = a01[e]; if (__any(v > r1[14])) ins15(r1, v);
            v = a11[e]; if (__any(v > r1[14])) ins15(r1, v);
        }
    }

    // Emit: partial[qrow][split][sub][15], sub = hi (s-row half within chunk rows)
    int q0 = qbase + rlo;
    float* dst0 = partial + (((size_t)q0 * NSPLIT + y) * 2 + hi) * 15;
    float* dst1 = partial + (((size_t)(q0 + 32) * NSPLIT + y) * 2 + hi) * 15;
#pragma unroll
    for (int i = 0; i < 15; ++i) { dst0[i] = r0[i]; dst1[i] = r1[i]; }
}

// ---------------- Final: merge 960 candidates/row -> top15 -> LSE/top4 loss ----------------
// Wave per row, 4 rows/block, no per-round barriers, one atomicAdd per block.
__global__ __launch_bounds__(256) void topk_loss(const float* __restrict__ partial,
                                                 float* __restrict__ accum) {
    int t = threadIdx.x, lane = t & 63, wid = t >> 6;
    int r = blockIdx.x * 4 + wid;
    const float* src = partial + (size_t)r * NCAND;
    float v[15];
#pragma unroll
    for (int i = 0; i < 15; ++i) v[i] = src[lane + 64 * i];
    float m0 = 0.f, sexp = 0.f, top4 = 0.f;
#pragma unroll
    for (int round = 0; round < 15; ++round) {
        float m = v[0];
        int mi = lane * 16;
#pragma unroll
        for (int i = 1; i < 15; ++i)
            if (v[i] > m) { m = v[i]; mi = lane * 16 + i; }
#pragma unroll
        for (int o = 32; o > 0; o >>= 1) {
            float om = __shfl_xor(m, o, 64);
            int oi = __shfl_xor(mi, o, 64);
            if (om > m || (om == m && oi < mi)) { m = om; mi = oi; }
        }
        int wl = mi >> 4, wi = mi & 15;
#pragma unroll
        for (int i = 0; i < 15; ++i)
            if (i == wi && wl == lane) v[i] = -1e30f;   // static-index clear
        if (round == 0) m0 = m;
        sexp += expf(m - m0);
        if (round < 4) top4 += m;
    }
    float loss = m0 + logf(sexp) - 0.25f * top4;
    __shared__ float red[4];
    if (lane == 0) red[wid] = loss;
    __syncthreads();
    if (t == 0) atomicAdd(accum, red[0] + red[1] + red[2] + red[3]);
}

__global__ void finalize_out(const float* __restrict__ accum, float* __restrict__ out) {
    out[0] = accum[0] * (1.0f / (float)NQ);
}

// ---------------- Launch ----------------
extern "C" void kernel_launch(void* const* d_in, const int* in_sizes, int n_in,
                              void* d_out, int out_size, void* d_ws, size_t ws_size,
                              hipStream_t stream) {
    (void)in_sizes; (void)n_in; (void)out_size; (void)ws_size;
    const float* q = (const float*)d_in[0];
    const float* S = (const float*)d_in[1];
    char* ws = (char*)d_ws;
    char* qn = ws;                                                   //  2,097,152 B
    char* sn = ws + 2097152;                                         // 20,971,520 B
    float* partial = (float*)(ws + 2097152 + 20971520);              // 15,728,640 B
    float* accum   = (float*)(ws + 2097152 + 20971520 + 15728640);   // 4 B

    hipMemsetAsync(accum, 0, 4, stream);
    pool_q_norm<<<512, 256, 0, stream>>>(q, qn);
    pool_s_norm<<<1024, 256, 0, stream>>>(S, sn);
    sim_topk<<<256, 512, 0, stream>>>(qn, sn, partial);
    topk_loss<<<NQ / 4, 256, 0, stream>>>(partial, accum);
    finalize_out<<<1, 1, 0, stream>>>(accum, (float*)d_out);
}

// Round 10
// 324.302 us; speedup vs baseline: 2.9431x; 1.0712x over previous
//
#include <hip/hip_runtime.h>
#include <hip/hip_bf16.h>
#include <stdint.h>

// Problem geometry (fixed by reference)
#define NQ 4096      // 64*8*8 query rows
#define NS 40960     // 32768 (s1) + 8192 (s_src)
#define CDIM 512
#define QT 256       // q rows per block: 4 waves x 64 q (2 groups of 32)
#define SC 64        // s rows per chunk
#define NSPLIT 32    // s-dimension splits
#define SPER (NS / NSPLIT)   // 1280
#define NCHUNK (SPER / SC)   // 20
#define NCAND 960    // per-row candidates: 32 splits * 2 lane-halves * 15

typedef float f32x16 __attribute__((ext_vector_type(16)));
typedef unsigned int u32x4 __attribute__((ext_vector_type(4)));
typedef unsigned int u32x2 __attribute__((ext_vector_type(2)));

__device__ __forceinline__ unsigned short f2bf(float f) {
    uint32_t u = __builtin_bit_cast(uint32_t, f);
    u += 0x7fffu + ((u >> 16) & 1u);   // RNE (finite values only here)
    return (unsigned short)(u >> 16);
}
__device__ __forceinline__ float bf2f(unsigned short u) {
    uint32_t x = ((uint32_t)u) << 16;
    return __builtin_bit_cast(float, x);
}
// k-permutation baked into BOTH qn and sn fp8 layouts (dot-product invariant):
// swap bits 3,4 of the channel index so one 16B LDS slot holds the two 8B
// MFMA operands (m=2kk, 2kk+1) for a lane's k-half.
__device__ __forceinline__ int kperm(int c) {
    return (c & ~24) | ((c & 8) << 1) | ((c & 16) >> 1);
}

// CK-proven cast pattern: generic -> AS1/AS3 via uintptr
__device__ __forceinline__ void async_load16(const void* g, void* l) {
    auto gp = reinterpret_cast<const __attribute__((address_space(1))) uint32_t*>(
        reinterpret_cast<uintptr_t>(g));
    auto lp = reinterpret_cast<__attribute__((address_space(3))) uint32_t*>(
        reinterpret_cast<uintptr_t>(l));
    __builtin_amdgcn_global_load_lds(gp, lp, 16 /*bytes, literal*/, 0, 0);
}

// Branchless sorted-desc insert: r[i] = med3(v, r[i-1], r[i]) for i=14..1, then max.
// Inserting v <= r[14] is a provable no-op, so a wave-uniform __any guard is exact.
__device__ __forceinline__ void ins15(float (&r)[15], float v) {
#pragma unroll
    for (int i = 14; i >= 1; --i) r[i] = __builtin_amdgcn_fmed3f(v, r[i - 1], r[i]);
    r[0] = fmaxf(r[0], v);
}

// ---------------- Phase A1: pool q (4x4 mean) + row-normalize -> fp8 (k-permuted) ----------------
__global__ __launch_bounds__(256) void pool_q_norm(const float* __restrict__ q,
                                                   char* __restrict__ qn) {
    int bb = blockIdx.x >> 3, h = blockIdx.x & 7;
    int t = threadIdx.x, lane = t & 63, wid = t >> 6;
    float vals[2][8];
    float ss[8] = {0, 0, 0, 0, 0, 0, 0, 0};
#pragma unroll
    for (int e = 0; e < 2; ++e) {
        int c = 2 * t + e;
        const float* base = q + ((size_t)(bb * 512 + c) * 1024 + 4 * h * 32);
#pragma unroll
        for (int w2 = 0; w2 < 8; ++w2) vals[e][w2] = 0.f;
#pragma unroll
        for (int i = 0; i < 4; ++i) {
            const float4* row = (const float4*)(base + i * 32);
#pragma unroll
            for (int w2 = 0; w2 < 8; ++w2) {
                float4 v = row[w2];
                vals[e][w2] += (v.x + v.y) + (v.z + v.w);
            }
        }
#pragma unroll
        for (int w2 = 0; w2 < 8; ++w2) {
            vals[e][w2] *= (1.f / 16.f);
            ss[w2] += vals[e][w2] * vals[e][w2];
        }
    }
    __shared__ float red[8][4];
#pragma unroll
    for (int k = 0; k < 8; ++k) {
        float v = ss[k];
#pragma unroll
        for (int o = 32; o > 0; o >>= 1) v += __shfl_xor(v, o, 64);
        if (lane == 0) red[k][wid] = v;
    }
    __syncthreads();
    int cp = kperm(2 * t);
#pragma unroll
    for (int w2 = 0; w2 < 8; ++w2) {
        float inv = rsqrtf(red[w2][0] + red[w2][1] + red[w2][2] + red[w2][3]);
        int p = __builtin_amdgcn_cvt_pk_fp8_f32(vals[0][w2] * inv, vals[1][w2] * inv, 0, false);
        *(unsigned short*)(qn + (size_t)(bb * 64 + h * 8 + w2) * 512 + cp) = (unsigned short)(p & 0xffff);
    }
}

// ------- Phase A2: pool S at BOTH scales + row-normalize -> fp8 (k-permuted) -------
__global__ __launch_bounds__(256) void pool_s_norm(const float* __restrict__ S,
                                                   char* __restrict__ sn) {
    int bb = blockIdx.x >> 3, h2 = blockIdx.x & 7;
    int t = threadIdx.x, lane = t & 63, wid = t >> 6;
    __shared__ unsigned short tile[40 * 512];   // 40KB raw-bf16 values
    __shared__ float rowsum[40];
#pragma unroll
    for (int e = 0; e < 2; ++e) {
        int c = 2 * t + e;
        const float* base = S + ((size_t)(bb * 512 + c) * 1024 + 4 * h2 * 32);
        float s1v[2][16];
#pragma unroll
        for (int j = 0; j < 2; ++j) {
            const float4* r0 = (const float4*)(base + (2 * j) * 32);
            const float4* r1 = (const float4*)(base + (2 * j + 1) * 32);
#pragma unroll
            for (int f = 0; f < 8; ++f) {
                float4 a = r0[f], b2 = r1[f];
                s1v[j][2 * f]     = (a.x + a.y + b2.x + b2.y) * 0.25f;
                s1v[j][2 * f + 1] = (a.z + a.w + b2.z + b2.w) * 0.25f;
            }
        }
#pragma unroll
        for (int j = 0; j < 2; ++j)
#pragma unroll
            for (int w1 = 0; w1 < 16; ++w1)
                tile[(j * 16 + w1) * 512 + c] = f2bf(s1v[j][w1]);
#pragma unroll
        for (int w2 = 0; w2 < 8; ++w2) {
            float src = (s1v[0][2 * w2] + s1v[0][2 * w2 + 1] +
                         s1v[1][2 * w2] + s1v[1][2 * w2 + 1]) * 0.25f;
            tile[(32 + w2) * 512 + c] = f2bf(src);
        }
    }
    __syncthreads();
    // Row sums-of-squares: wave wid owns rows 4k+wid; 64 lanes x 8 bf16 per row.
#pragma unroll
    for (int k = 0; k < 10; ++k) {
        int row = 4 * k + wid;
        u32x4 d = *(const u32x4*)(&tile[row * 512 + lane * 8]);
        float s = 0.f;
#pragma unroll
        for (int j = 0; j < 4; ++j) {
            float x0 = bf2f((unsigned short)(d[j] & 0xffffu));
            float x1 = bf2f((unsigned short)(d[j] >> 16));
            s += x0 * x0 + x1 * x1;
        }
#pragma unroll
        for (int o = 32; o > 0; o >>= 1) s += __shfl_xor(s, o, 64);
        if (lane == 0) rowsum[row] = s;
    }
    __syncthreads();
    // Scale + fp8 cast + k-permuted coalesced 8B stores: 40 rows x 64 segs.
#pragma unroll
    for (int k = 0; k < 10; ++k) {
        int idx = t + 256 * k;
        int r = idx >> 6, seg = idx & 63;
        float inv = rsqrtf(rowsum[r]);
        const unsigned short* src = &tile[r * 512 + seg * 8];
        float x[8];
#pragma unroll
        for (int m = 0; m < 8; ++m) x[m] = bf2f(src[m]) * inv;
        unsigned int w0 = (unsigned int)__builtin_amdgcn_cvt_pk_fp8_f32(
            x[2], x[3], __builtin_amdgcn_cvt_pk_fp8_f32(x[0], x[1], 0, false), true);
        unsigned int w1 = (unsigned int)__builtin_amdgcn_cvt_pk_fp8_f32(
            x[6], x[7], __builtin_amdgcn_cvt_pk_fp8_f32(x[4], x[5], 0, false), true);
        int nseg = (seg & ~3) | ((seg & 1) << 1) | ((seg >> 1) & 1);   // swap k-bits 3,4
        int grow = (r < 32) ? (bb * 256 + (2 * h2 + (r >> 4)) * 16 + (r & 15))
                            : (32768 + bb * 64 + h2 * 8 + (r - 32));
        uint2 o2; o2.x = w0; o2.y = w1;
        *(uint2*)(sn + (size_t)grow * 512 + nseg * 8) = o2;
    }
}

// ---------------- Phase B: fp8 32x32x16 MFMA + in-register top-15 ----------------
// 512 blocks x 256 threads (4 waves x 64 q = 256-q tile), 2 blocks/CU.
// Two INDEPENDENT barrier groups per CU: while one block is in its scan/stage/
// barrier window, the other block's waves feed the matrix pipe (fixes R9's
// lockstep idle — MfmaUtil 32% with 1x8-wave block).
// XCD-pinned: the 16 x-tiles of each s-split y run on one XCD (id&7).
// LDS chunk = 64 s-rows x 512B fp8 = 32KB (dbuf, 64KB/block; 2 blocks = 128KB).
// b[2][16] u32x4 = 128 VGPR + 64 acc: ~230 unified regs -> 8 waves/CU bracket.
// Full slot^(row&31) swizzle: conflict-free ds_read_b128 (R9 measured 0).
__global__ __launch_bounds__(256, 2) void sim_topk(const char* __restrict__ qn,
                                                   const char* __restrict__ sn,
                                                   float* __restrict__ partial) {
    __shared__ char Bs[2][SC * 512];   // 2 x 32KB
    int id = blockIdx.x;
    int xcd = id & 7, j = id >> 3;
    int y = xcd * 4 + (j & 3);        // s-split 0..31, pinned to XCD
    int x = j >> 2;                   // q-tile 0..15
    int tid = threadIdx.x, lane = tid & 63, wid = tid >> 6;
    int rlo = lane & 31, hi = lane >> 5;
    int qbase = x * QT + wid * 64;
    int sbase = y * SPER;
    char* BsB = &Bs[0][0];

    // B fragments (q side, fp8): 2 groups x 32 q rows, full K=512 (k-permuted layout).
    // One u32x4 per (g,kk) covers MFMAs 2kk (lo u64) and 2kk+1 (hi u64).
    u32x4 b[2][16];
#pragma unroll
    for (int g = 0; g < 2; ++g) {
        const char* qp = qn + (size_t)(qbase + g * 32 + rlo) * 512 + hi * 16;
#pragma unroll
        for (int kk = 0; kk < 16; ++kk) b[g][kk] = *(const u32x4*)(qp + kk * 32);
    }

    float r0[15], r1[15];
#pragma unroll
    for (int i = 0; i < 15; ++i) { r0[i] = -2.0f; r1[i] = -2.0f; }

    auto stage = [&](int ch, int buf) {
#pragma unroll
        for (int ii = 0; ii < 8; ++ii) {
            int i = wid * 8 + ii;                 // wave-uniform instr idx, 2 rows each
            int row = 2 * i + hi;
            size_t srcoff = (size_t)(sbase + ch * SC + row) * 512
                          + (size_t)((rlo ^ (row & 31)) * 16);
            async_load16(sn + srcoff, BsB + buf * 32768 + i * 1024);
        }
    };

    stage(0, 0);
    stage(1, 1);
    for (int ch = 0; ch < NCHUNK; ++ch) {
        int buf = ch & 1;
        asm volatile("s_waitcnt vmcnt(8)" ::: "memory");   // chunk ch's loads landed
        __builtin_amdgcn_s_barrier();
        // Pin B-frags resident (defeat remat); zero-cost.
#pragma unroll
        for (int g = 0; g < 2; ++g)
#pragma unroll
            for (int kk = 0; kk < 16; ++kk) asm volatile("" : "+v"(b[g][kk]));
        const char* B0 = BsB + buf * 32768;
        f32x16 a00, a01, a10, a11;   // acc[sgroup][qgroup]
#pragma unroll
        for (int e = 0; e < 16; ++e) { a00[e] = 0.f; a01[e] = 0.f; a10[e] = 0.f; a11[e] = 0.f; }
        __builtin_amdgcn_s_setprio(1);
#pragma unroll
        for (int kk = 0; kk < 16; ++kk) {
            int slot = ((kk * 2 + hi) ^ rlo) * 16;
            u32x4 aA = *(const u32x4*)(B0 + rlo * 512 + slot);
            u32x4 aB = *(const u32x4*)(B0 + (32 + rlo) * 512 + slot);
            long aAlo = __builtin_bit_cast(long, (u32x2){aA[0], aA[1]});
            long aAhi = __builtin_bit_cast(long, (u32x2){aA[2], aA[3]});
            long aBlo = __builtin_bit_cast(long, (u32x2){aB[0], aB[1]});
            long aBhi = __builtin_bit_cast(long, (u32x2){aB[2], aB[3]});
            long b0lo = __builtin_bit_cast(long, (u32x2){b[0][kk][0], b[0][kk][1]});
            long b0hi = __builtin_bit_cast(long, (u32x2){b[0][kk][2], b[0][kk][3]});
            long b1lo = __builtin_bit_cast(long, (u32x2){b[1][kk][0], b[1][kk][1]});
            long b1hi = __builtin_bit_cast(long, (u32x2){b[1][kk][2], b[1][kk][3]});
            // lo-sweep then hi-sweep: no back-to-back same-accumulator MFMAs
            a00 = __builtin_amdgcn_mfma_f32_32x32x16_fp8_fp8(aAlo, b0lo, a00, 0, 0, 0);
            a01 = __builtin_amdgcn_mfma_f32_32x32x16_fp8_fp8(aAlo, b1lo, a01, 0, 0, 0);
            a10 = __builtin_amdgcn_mfma_f32_32x32x16_fp8_fp8(aBlo, b0lo, a10, 0, 0, 0);
            a11 = __builtin_amdgcn_mfma_f32_32x32x16_fp8_fp8(aBlo, b1lo, a11, 0, 0, 0);
            a00 = __builtin_amdgcn_mfma_f32_32x32x16_fp8_fp8(aAhi, b0hi, a00, 0, 0, 0);
            a01 = __builtin_amdgcn_mfma_f32_32x32x16_fp8_fp8(aAhi, b1hi, a01, 0, 0, 0);
            a10 = __builtin_amdgcn_mfma_f32_32x32x16_fp8_fp8(aBhi, b0hi, a10, 0, 0, 0);
            a11 = __builtin_amdgcn_mfma_f32_32x32x16_fp8_fp8(aBhi, b1hi, a11, 0, 0, 0);
        }
        __builtin_amdgcn_s_setprio(0);
        __builtin_amdgcn_s_barrier();   // all reads of this buffer retired
        { int n = ch + 2; if (n >= NCHUNK) n -= NCHUNK; stage(n, buf); }  // refill freed buf
        // Scan overlaps the in-flight staging loads. List = q-group.
#pragma unroll
        for (int e = 0; e < 16; ++e) {
            float v;
            v = a00[e]; if (__any(v > r0[14])) ins15(r0, v);
            v = a10[e]; if (__any(v > r0[14])) ins15(r0, v);
            v = a01[e]; if (__any(v > r1[14])) ins15(r1, v);
            v = a11[e]; if (__any(v > r1[14])) ins15(r1, v);
        }
    }

    // Emit: partial[qrow][split][sub][15], sub = hi (s-row half within chunk rows)
    int q0 = qbase + rlo;
    float* dst0 = partial + (((size_t)q0 * NSPLIT + y) * 2 + hi) * 15;
    float* dst1 = partial + (((size_t)(q0 + 32) * NSPLIT + y) * 2 + hi) * 15;
#pragma unroll
    for (int i = 0; i < 15; ++i) { dst0[i] = r0[i]; dst1[i] = r1[i]; }
}

// ---------------- Final: merge 960 candidates/row -> top15 -> LSE/top4 loss ----------------
// Wave per row, 4 rows/block, no per-round barriers, one atomicAdd per block.
__global__ __launch_bounds__(256) void topk_loss(const float* __restrict__ partial,
                                                 float* __restrict__ accum) {
    int t = threadIdx.x, lane = t & 63, wid = t >> 6;
    int r = blockIdx.x * 4 + wid;
    const float* src = partial + (size_t)r * NCAND;
    float v[15];
#pragma unroll
    for (int i = 0; i < 15; ++i) v[i] = src[lane + 64 * i];
    float m0 = 0.f, sexp = 0.f, top4 = 0.f;
#pragma unroll
    for (int round = 0; round < 15; ++round) {
        float m = v[0];
        int mi = lane * 16;
#pragma unroll
        for (int i = 1; i < 15; ++i)
            if (v[i] > m) { m = v[i]; mi = lane * 16 + i; }
#pragma unroll
        for (int o = 32; o > 0; o >>= 1) {
            float om = __shfl_xor(m, o, 64);
            int oi = __shfl_xor(mi, o, 64);
            if (om > m || (om == m && oi < mi)) { m = om; mi = oi; }
        }
        int wl = mi >> 4, wi = mi & 15;
#pragma unroll
        for (int i = 0; i < 15; ++i)
            if (i == wi && wl == lane) v[i] = -1e30f;   // static-index clear
        if (round == 0) m0 = m;
        sexp += expf(m - m0);
        if (round < 4) top4 += m;
    }
    float loss = m0 + logf(sexp) - 0.25f * top4;
    __shared__ float red[4];
    if (lane == 0) red[wid] = loss;
    __syncthreads();
    if (t == 0) atomicAdd(accum, red[0] + red[1] + red[2] + red[3]);
}

__global__ void finalize_out(const float* __restrict__ accum, float* __restrict__ out) {
    out[0] = accum[0] * (1.0f / (float)NQ);
}

// ---------------- Launch ----------------
extern "C" void kernel_launch(void* const* d_in, const int* in_sizes, int n_in,
                              void* d_out, int out_size, void* d_ws, size_t ws_size,
                              hipStream_t stream) {
    (void)in_sizes; (void)n_in; (void)out_size; (void)ws_size;
    const float* q = (const float*)d_in[0];
    const float* S = (const float*)d_in[1];
    char* ws = (char*)d_ws;
    char* qn = ws;                                                   //  2,097,152 B
    char* sn = ws + 2097152;                                         // 20,971,520 B
    float* partial = (float*)(ws + 2097152 + 20971520);              // 15,728,640 B
    float* accum   = (float*)(ws + 2097152 + 20971520 + 15728640);   // 4 B

    hipMemsetAsync(accum, 0, 4, stream);
    pool_q_norm<<<512, 256, 0, stream>>>(q, qn);
    pool_s_norm<<<1024, 256, 0, stream>>>(S, sn);
    sim_topk<<<512, 256, 0, stream>>>(qn, sn, partial);
    topk_loss<<<NQ / 4, 256, 0, stream>>>(partial, accum);
    finalize_out<<<1, 1, 0, stream>>>(accum, (float*)d_out);
}